// Round 3
// baseline (1008.445 us; speedup 1.0000x reference)
//
#include <hip/hip_runtime.h>

// Green-Ampt infiltration scan. B=16384 rows x T=2048 sequential steps.
// One thread per row. Key points:
//  - Full-line output batching: each batch produces exactly 128B (32 floats)
//    per output stream per lane; the 8 16B stores per stream are issued
//    back-to-back (nontemporal) so L2 lines complete before set-conflict
//    eviction (R1 showed 1.88x write amplification from interleaved stores).
//  - v_rcp_f32 instead of IEEE div: serial recurrence chain ~2x shorter;
//    error ~1e-7/step, irrelevant vs 2% absmax threshold.
//  - Native clang vector type (ext_vector_type) because
//    __builtin_nontemporal_store rejects HIP_vector_type<float,4>.

#define GA_MIN_INF 0.1f
#define GA_EPS 1e-6f

typedef float f4 __attribute__((ext_vector_type(4)));

constexpr int BATCH = 8;  // f4 chunks per batch = 32 floats = 128B = 1 line

__global__ __launch_bounds__(64, 1) void ga_scan_kernel(
    const float* __restrict__ precip,
    const float* __restrict__ K,
    const float* __restrict__ psi,
    const float* __restrict__ dtheta,
    float* __restrict__ out,
    int B, int T) {
  int b = blockIdx.x * 64 + threadIdx.x;
  if (b >= B) return;

  const float Kv = K[b];
  const float pd = psi[b] * dtheta[b];
  const float kpd = Kv * pd;

  const size_t rowoff = (size_t)b * (size_t)T;
  const f4* __restrict__ pr = reinterpret_cast<const f4*>(precip + rowoff);
  f4* o_infil  = reinterpret_cast<f4*>(out + rowoff);
  f4* o_runoff = reinterpret_cast<f4*>(out + (size_t)B * (size_t)T + rowoff);
  f4* o_cumF   = reinterpret_cast<f4*>(out + 2ull * (size_t)B * (size_t)T + rowoff);

  const int nchunk = T >> 2;        // f4 chunks per row
  const int nb = nchunk / BATCH;    // batches per row (T=2048 -> 64)

  float F = 0.0f;

  f4 buf[BATCH];
#pragma unroll
  for (int i = 0; i < BATCH; ++i) buf[i] = pr[i];

  for (int kb = 0; kb < nb; ++kb) {
    // Prefetch next batch (independent of the recurrence chain).
    f4 nxt[BATCH];
    if (kb + 1 < nb) {
#pragma unroll
      for (int i = 0; i < BATCH; ++i) nxt[i] = pr[(kb + 1) * BATCH + i];
    }

    // Compute the 32 recurrence steps into registers.
    f4 fi[BATCH], ro[BATCH], cf[BATCH];
#pragma unroll
    for (int i = 0; i < BATCH; ++i) {
      const f4 p = buf[i];
#pragma unroll
      for (int j = 0; j < 4; ++j) {
        float pv   = p[j];
        float rF   = __builtin_amdgcn_rcpf(fmaxf(F, GA_EPS));
        float fcap = fmaxf(Kv + kpd * rF, GA_MIN_INF);
        float fact = fminf(pv, fcap);
        float rr   = fmaxf(pv - fact, 0.0f);
        F += fact;
        fi[i][j] = fact; ro[i][j] = rr; cf[i][j] = F;
      }
    }

    // Burst the three full lines, one stream at a time, nontemporal.
    const int base = kb * BATCH;
#pragma unroll
    for (int i = 0; i < BATCH; ++i)
      __builtin_nontemporal_store(fi[i], &o_infil[base + i]);
#pragma unroll
    for (int i = 0; i < BATCH; ++i)
      __builtin_nontemporal_store(ro[i], &o_runoff[base + i]);
#pragma unroll
    for (int i = 0; i < BATCH; ++i)
      __builtin_nontemporal_store(cf[i], &o_cumF[base + i]);

#pragma unroll
    for (int i = 0; i < BATCH; ++i) buf[i] = nxt[i];
  }
}

extern "C" void kernel_launch(void* const* d_in, const int* in_sizes, int n_in,
                              void* d_out, int out_size, void* d_ws, size_t ws_size,
                              hipStream_t stream) {
  const float* precip = (const float*)d_in[0];
  const float* K      = (const float*)d_in[1];
  const float* psi    = (const float*)d_in[2];
  const float* dtheta = (const float*)d_in[3];
  float* out = (float*)d_out;

  const int B = in_sizes[1];            // K has B elements
  const int T = in_sizes[0] / B;        // precip is B*T

  const int block = 64;
  const int grid = (B + block - 1) / block;
  ga_scan_kernel<<<grid, block, 0, stream>>>(precip, K, psi, dtheta, out, B, T);
}

// Round 4
// 176.595 us; speedup vs baseline: 5.7105x; 5.7105x over previous
//
#include <hip/hip_runtime.h>

// Green-Ampt infiltration scan. B=16384 rows x T=2048 sequential steps.
// One wave (64 threads) per 64 consecutive rows; 1 block per CU.
//
// R1/R3 lesson: per-lane row-major 16B stores (rows 8KiB apart, all lanes at
// the same t-phase) collapse into ~32 L2 set-groups -> partial-line evictions
// -> 1.88x HBM write amplification (3.56x with nontemporal, which skips L2
// write-combining entirely).
//
// Fix: LDS transpose. Per 64-step time batch, each lane writes its row's
// results (packed f4, ds_write_b128) into [64][68]-padded LDS tiles, then the
// wave cooperatively stores transposed: 16 lanes cover 256B contiguous per
// row-chunk -> every HBM line written once, fully.

#define GA_MIN_INF 0.1f
#define GA_EPS 1e-6f

typedef float f4 __attribute__((ext_vector_type(4)));

constexpr int TB  = 64;  // time-steps per batch (= 256B per row per stream)
constexpr int PAD = 68;  // padded row length (bytes 272: 16B-aligned, banks spread)

__global__ __launch_bounds__(64, 1) void ga_scan_kernel(
    const float* __restrict__ precip,
    const float* __restrict__ K,
    const float* __restrict__ psi,
    const float* __restrict__ dtheta,
    float* __restrict__ out,
    int B, int T) {
  __shared__ float s_fi[64 * PAD];
  __shared__ float s_ro[64 * PAD];
  __shared__ float s_cf[64 * PAD];

  const int lane = threadIdx.x;
  const int rowbase = blockIdx.x * 64;
  const int b = rowbase + lane;

  const float Kv = K[b];
  const float pd = psi[b] * dtheta[b];
  const float kpd = Kv * pd;

  const f4* __restrict__ pr = reinterpret_cast<const f4*>(precip + (size_t)b * T);

  const size_t BT = (size_t)B * (size_t)T;
  float* const o0 = out;              // infiltration
  float* const o1 = out + BT;         // runoff
  float* const o2 = out + 2 * BT;     // cumulative F

  // Output-phase mapping: lane covers row (g*4 + orow), t-chunk ocol..ocol+3.
  const int orow = lane >> 4;         // 0..3
  const int ocol = (lane & 15) * 4;   // 0,4,...,60

  const int nbatch = T / TB;          // 32
  float F = 0.0f;

  // Prefetch first half-batch (8 f4 = 32 floats).
  f4 buf[8], nxt[8];
#pragma unroll
  for (int i = 0; i < 8; ++i) buf[i] = pr[i];

  for (int kb = 0; kb < nbatch; ++kb) {
#pragma unroll
    for (int h = 0; h < 2; ++h) {
      const int sb = kb * 2 + h;      // current half-batch index
      if (sb + 1 < nbatch * 2) {
#pragma unroll
        for (int i = 0; i < 8; ++i) nxt[i] = pr[(sb + 1) * 8 + i];
      }
      // 32 recurrence steps; pack every 4 into f4 and ds_write_b128.
#pragma unroll
      for (int i = 0; i < 8; ++i) {
        const f4 p = buf[i];
        f4 fi4, ro4, cf4;
#pragma unroll
        for (int j = 0; j < 4; ++j) {
          float pv   = p[j];
          float rF   = __builtin_amdgcn_rcpf(fmaxf(F, GA_EPS));
          float fcap = fmaxf(Kv + kpd * rF, GA_MIN_INF);
          float fact = fminf(pv, fcap);
          float rr   = fmaxf(pv - fact, 0.0f);
          F += fact;
          fi4[j] = fact; ro4[j] = rr; cf4[j] = F;
        }
        const int t0 = h * 32 + i * 4;
        *reinterpret_cast<f4*>(&s_fi[lane * PAD + t0]) = fi4;
        *reinterpret_cast<f4*>(&s_ro[lane * PAD + t0]) = ro4;
        *reinterpret_cast<f4*>(&s_cf[lane * PAD + t0]) = cf4;
      }
#pragma unroll
      for (int i = 0; i < 8; ++i) buf[i] = nxt[i];
    }

    __syncthreads();

    // Transposed, fully-coalesced output: 16 lanes x 16B = 256B per row-chunk.
    const int tb = kb * TB;
#pragma unroll
    for (int g = 0; g < 16; ++g) {
      const int r = g * 4 + orow;                    // row within the wave's 64
      const size_t go = (size_t)(rowbase + r) * T + tb + ocol;
      const int lo = r * PAD + ocol;
      f4 vfi = *reinterpret_cast<const f4*>(&s_fi[lo]);
      f4 vro = *reinterpret_cast<const f4*>(&s_ro[lo]);
      f4 vcf = *reinterpret_cast<const f4*>(&s_cf[lo]);
      *reinterpret_cast<f4*>(o0 + go) = vfi;
      *reinterpret_cast<f4*>(o1 + go) = vro;
      *reinterpret_cast<f4*>(o2 + go) = vcf;
    }

    __syncthreads();
  }
}

extern "C" void kernel_launch(void* const* d_in, const int* in_sizes, int n_in,
                              void* d_out, int out_size, void* d_ws, size_t ws_size,
                              hipStream_t stream) {
  const float* precip = (const float*)d_in[0];
  const float* K      = (const float*)d_in[1];
  const float* psi    = (const float*)d_in[2];
  const float* dtheta = (const float*)d_in[3];
  float* out = (float*)d_out;

  const int B = in_sizes[1];            // K has B elements
  const int T = in_sizes[0] / B;        // precip is B*T

  const int block = 64;
  const int grid = B / block;           // 256 blocks -> 1 wave per CU
  ga_scan_kernel<<<grid, block, 0, stream>>>(precip, K, psi, dtheta, out, B, T);
}